// Round 1
// baseline (143.348 us; speedup 1.0000x reference)
//
#include <hip/hip_runtime.h>

#define BB 4
#define TT 64
#define SS 256
#define DD 512
#define FEMB 128

__device__ __forceinline__ float fast_tanh(float x) {
    // clamp so exp never overflows; tanh(10) == 1.0f in fp32 anyway
    x = fminf(fmaxf(x, -10.f), 10.f);
    float t = __expf(2.f * x);
    return (t - 1.f) / (t + 1.f);
}

// Fused 4-GEMM + bias + tanh.  C = tanh(A @ W^T + b), A:[M,K] row-major, W:[512,K] row-major.
// z=0: H  = tanh(X @ W1^T + b1)   M=1024 K=512
// z=1: Fo = tanh(Z @ W3^T + b3)   M=1024 K=128
// z=2: O2 = tanh(Y @ W2^T + b2)   M=256  K=512
// z=3: O3 = tanh(Y @ W4^T + b4)   M=256  K=512
__global__ __launch_bounds__(256) void gemm_tanh_kernel(
    const float* __restrict__ X, const float* __restrict__ Z, const float* __restrict__ Y,
    const float* __restrict__ W1, const float* __restrict__ b1,
    const float* __restrict__ W2, const float* __restrict__ b2,
    const float* __restrict__ W3, const float* __restrict__ b3,
    const float* __restrict__ W4, const float* __restrict__ b4,
    float* __restrict__ H, float* __restrict__ Fo,
    float* __restrict__ O2, float* __restrict__ O3)
{
    const float* A; const float* W; const float* bias; float* C; int M; int K;
    switch (blockIdx.z) {
      case 0:  A = X; W = W1; bias = b1; C = H;  M = 1024; K = 512; break;
      case 1:  A = Z; W = W3; bias = b3; C = Fo; M = 1024; K = 128; break;
      case 2:  A = Y; W = W2; bias = b2; C = O2; M = 256;  K = 512; break;
      default: A = Y; W = W4; bias = b4; C = O3; M = 256;  K = 512; break;
    }
    const int m0 = blockIdx.y * 64;
    if (m0 >= M) return;
    const int n0 = blockIdx.x * 64;

    // +4 pad keeps float4 alignment while breaking the worst bank strides
    __shared__ float As[16][68];
    __shared__ float Ws[16][68];

    const int tid  = threadIdx.x;
    const int lrow = tid >> 2;   // 0..63  (tile row for loading)
    const int lkv  = tid & 3;    // 0..3   (which float4 chunk of the 16-wide K slab)
    const int ty   = tid >> 4;   // 0..15  (micro-tile row group)
    const int tx   = tid & 15;   // 0..15  (micro-tile col group)

    float acc[4][4] = {};

    for (int k0 = 0; k0 < K; k0 += 16) {
        float4 av = *(const float4*)&A[(m0 + lrow) * K + k0 + lkv * 4];
        float4 wv = *(const float4*)&W[(n0 + lrow) * K + k0 + lkv * 4];
        __syncthreads();   // previous iter's compute reads done before overwrite
        As[lkv*4+0][lrow] = av.x; As[lkv*4+1][lrow] = av.y;
        As[lkv*4+2][lrow] = av.z; As[lkv*4+3][lrow] = av.w;
        Ws[lkv*4+0][lrow] = wv.x; Ws[lkv*4+1][lrow] = wv.y;
        Ws[lkv*4+2][lrow] = wv.z; Ws[lkv*4+3][lrow] = wv.w;
        __syncthreads();
        #pragma unroll
        for (int k = 0; k < 16; ++k) {
            float4 a4 = *(const float4*)&As[k][ty * 4];
            float4 w4 = *(const float4*)&Ws[k][tx * 4];
            float a[4] = {a4.x, a4.y, a4.z, a4.w};
            float w[4] = {w4.x, w4.y, w4.z, w4.w};
            #pragma unroll
            for (int i = 0; i < 4; ++i)
                #pragma unroll
                for (int j = 0; j < 4; ++j)
                    acc[i][j] = fmaf(a[i], w[j], acc[i][j]);
        }
    }

    float4 bb = *(const float4*)&bias[n0 + tx * 4];
    float bj[4] = {bb.x, bb.y, bb.z, bb.w};
    #pragma unroll
    for (int i = 0; i < 4; ++i) {
        const int m = m0 + ty * 4 + i;
        float4 o;
        o.x = fast_tanh(acc[i][0] + bj[0]);
        o.y = fast_tanh(acc[i][1] + bj[1]);
        o.z = fast_tanh(acc[i][2] + bj[2]);
        o.w = fast_tanh(acc[i][3] + bj[3]);
        *(float4*)&C[m * DD + n0 + tx * 4] = o;
    }
}

// Attention: for each (b,t,d):  attn = sum_s softmax_s(H[b,s,d]*u + F[b,s,d]*v) * enc[b,s,d]
// where u = O2[b,t,d], v = O3[b,t,d].  |w| <= 2 so no max-subtraction needed.
// Block = (b, 4-wide t tile, 128-wide d quarter).  XCD swizzle: b = bits[2:1] of blockIdx
// so each b's 1.5 MB (H+F+enc slices) lives on 2 XCDs' L2.
__global__ __launch_bounds__(128) void attn_kernel(
    const float* __restrict__ H, const float* __restrict__ Fo,
    const float* __restrict__ X,   // enc, [1024,512] flat
    const float* __restrict__ O2, const float* __restrict__ O3,
    const float* __restrict__ Y,   // original "output" tensor [256,512] flat
    float* __restrict__ out)       // concat at 0 (B*T*1024), attn at 262144 (B*T*512)
{
    const int idx = blockIdx.x;                    // 0..255
    const int b   = (idx & 7) >> 1;                // 0..3   (XCD-pair per b)
    const int rem = ((idx >> 3) << 1) | (idx & 1); // 0..63
    const int t0  = (rem >> 2) * 4;                // 0,4,...,60
    const int d   = (rem & 3) * 128 + threadIdx.x; // 0..511

    float u[4], v[4];
    #pragma unroll
    for (int j = 0; j < 4; ++j) {
        const int bt = b * TT + t0 + j;
        u[j] = O2[bt * DD + d];
        v[j] = O3[bt * DD + d];
    }

    float l[4]   = {0.f, 0.f, 0.f, 0.f};
    float acc[4] = {0.f, 0.f, 0.f, 0.f};
    const float* Hb = H  + (b * SS) * DD + d;
    const float* Fb = Fo + (b * SS) * DD + d;
    const float* Eb = X  + (b * SS) * DD + d;

    #pragma unroll 4
    for (int s = 0; s < SS; ++s) {
        const float h = Hb[s * DD];
        const float f = Fb[s * DD];
        const float e = Eb[s * DD];
        #pragma unroll
        for (int j = 0; j < 4; ++j) {
            const float w  = fmaf(h, u[j], f * v[j]);
            const float ex = __expf(w);
            l[j]  += ex;
            acc[j] = fmaf(ex, e, acc[j]);
        }
    }

    #pragma unroll
    for (int j = 0; j < 4; ++j) {
        const int bt = b * TT + t0 + j;
        const float a = acc[j] / l[j];
        out[BB * TT * 2 * DD + bt * DD + d] = a;       // attn output (chunk 1)
        out[bt * 2 * DD + DD + d]           = a;       // concat second half
        out[bt * 2 * DD + d]                = Y[bt * DD + d]; // concat first half
    }
}

extern "C" void kernel_launch(void* const* d_in, const int* in_sizes, int n_in,
                              void* d_out, int out_size, void* d_ws, size_t ws_size,
                              hipStream_t stream)
{
    const float* Y  = (const float*)d_in[0];   // output          [4,64,512]
    const float* X  = (const float*)d_in[1];   // encoder_hidden  [256,4,512] == [1024,512] flat
    const float* Z  = (const float*)d_in[2];   // input_z         [4,256,128] == [1024,128] flat
    const float* W1 = (const float*)d_in[3];
    const float* b1 = (const float*)d_in[4];
    const float* W2 = (const float*)d_in[5];
    const float* b2 = (const float*)d_in[6];
    const float* W3 = (const float*)d_in[7];
    const float* b3 = (const float*)d_in[8];
    const float* W4 = (const float*)d_in[9];
    const float* b4 = (const float*)d_in[10];
    float* out = (float*)d_out;

    float* H  = (float*)d_ws;            // [1024,512]
    float* Fo = H  + 1024 * 512;         // [1024,512]
    float* O2 = Fo + 1024 * 512;         // [256,512]
    float* O3 = O2 + 256 * 512;          // [256,512]

    dim3 ggrid(8, 16, 4);
    gemm_tanh_kernel<<<ggrid, 256, 0, stream>>>(X, Z, Y, W1, b1, W2, b2, W3, b3, W4, b4,
                                                H, Fo, O2, O3);
    attn_kernel<<<256, 128, 0, stream>>>(H, Fo, X, O2, O3, Y, out);
}